// Round 16
// baseline (6705.430 us; speedup 1.0000x reference)
//
#include <hip/hip_runtime.h>

// Shapes (fixed by the problem)
#define Bx 16
#define Cx 256
#define Dx 32
#define Nx 2304   // 48*48

typedef _Float16 f16;
typedef _Float16 f16x4 __attribute__((ext_vector_type(4)));
typedef _Float16 f16x8 __attribute__((ext_vector_type(8)));
typedef float    f32x4 __attribute__((ext_vector_type(4)));
typedef float    f32x16 __attribute__((ext_vector_type(16)));
typedef unsigned int u32x2 __attribute__((ext_vector_type(2)));
typedef unsigned int u32x4 __attribute__((ext_vector_type(4)));

// A,B fragment layouts (gfx950):
//  A: lane holds A[m=lane%32][k=(lane/32)*8 + 0..7]  (f16x8)
//  B: lane holds B[k=(lane/32)*8 + 0..7][n=lane%32]  — same per-lane pattern.
//  C/D: col=lane&31, row=(reg&3)+8*(reg>>2)+4*(lane>>5)  [verified]
#define MFMA_K16(a, b, c) __builtin_amdgcn_mfma_f32_32x32x16_f16((a), (b), (c), 0, 0, 0)
#define EXP2F(x) __builtin_amdgcn_exp2f(x)
#define PKRTZ_U32(lo, hi) __builtin_bit_cast(unsigned, __builtin_amdgcn_cvt_pkrtz((lo), (hi)))

// Repack K8-layout P dwords into one f16x8 K16 B-frag via cross-half permlane
// swap. (R12/R14-verified path.)
__device__ __forceinline__ f16x8 swap_pack4(unsigned a0, unsigned a1,
                                            unsigned b0, unsigned b1) {
    asm("v_permlane32_swap_b32 %0, %1" : "+v"(a0), "+v"(b0));
    asm("v_permlane32_swap_b32 %0, %1" : "+v"(a1), "+v"(b1));
    u32x4 r = {a0, a1, b0, b1};
    return __builtin_bit_cast(f16x8, r);
}

// XCD-aware logical block id (T1, R14-verified).
__device__ __forceinline__ int xcd_swz(int nwg8) {
    int bid = blockIdx.x;
    return (bid & 7) * nwg8 + (bid >> 3);
}

// ---------------------------------------------------------------------------
// Kernel P: pack Wall = [Wq*(1/ln2); Wk; Wv] (320x256) to f16 + bias vector.
// ---------------------------------------------------------------------------
__global__ __launch_bounds__(256) void wall_prep(
    const float* __restrict__ Wq, const float* __restrict__ bq,
    const float* __restrict__ Wk, const float* __restrict__ bk,
    const float* __restrict__ Wv, const float* __restrict__ bv,
    f16* __restrict__ Wall, float* __restrict__ bias_all) {
    int r = blockIdx.x;
    int t = threadIdx.x;
    const float SC = 1.4426950408889634f;  // 1/ln2 folded into q rows
    const float* src;
    float scale, bsc;
    if (r < 32)      { src = Wq + (size_t)r * Cx;        scale = SC;  bsc = bq[r] * SC; }
    else if (r < 64) { src = Wk + (size_t)(r - 32) * Cx; scale = 1.f; bsc = bk[r - 32]; }
    else             { src = Wv + (size_t)(r - 64) * Cx; scale = 1.f; bsc = bv[r - 64]; }
    Wall[(size_t)r * Cx + t] = (f16)(src[t] * scale);
    if (t == 0) bias_all[r] = bsc;
}

// ---------------------------------------------------------------------------
// Kernel G: unified projection GEMM (R14-passing, unchanged).
// grid: Bx * 10 * 9 = 1440 blocks, 256 threads.
// ---------------------------------------------------------------------------
#define PG_ROWLEN 24
__global__ __launch_bounds__(256) void proj_gemm(
    const float* __restrict__ x,
    const f16* __restrict__ Wall, const float* __restrict__ bias_all,
    f16* __restrict__ qws, f16* __restrict__ kws, f16* __restrict__ vws) {
    __shared__ __align__(16) f16 xs[256 * PG_ROWLEN];   // 12 KB
    int bid = xcd_swz(180);            // 1440/8
    int nt = bid % 9;   bid /= 9;
    int rt = bid % 10;  bid /= 10;
    int b  = bid;
    int n0 = nt * 256;
    int r0 = rt * 32;
    int t  = threadIdx.x;
    int wv = t >> 6, il = t & 31, h = (t >> 5) & 1;

    const float* xb = x + (size_t)b * Cx * Nx + n0 + t;         // column gather
    const f16*   wp = Wall + (size_t)(r0 + il) * Cx + h * 8;    // frag row

    f32x16 acc[2];
    acc[0] = (f32x16){};
    acc[1] = (f32x16){};
    int nb = wv * 64 + il;   // frag n-row base (second frag adds 32)

    for (int ks = 0; ks < 16; ++ks) {
        float xv[16];
#pragma unroll
        for (int kk = 0; kk < 16; ++kk)
            xv[kk] = xb[(size_t)(ks * 16 + kk) * Nx];
        f16x8 p0, p1;
#pragma unroll
        for (int kk = 0; kk < 8; ++kk) {
            p0[kk] = (f16)xv[kk];
            p1[kk] = (f16)xv[8 + kk];
        }
        __syncthreads();
        *(f16x8*)&xs[t * PG_ROWLEN]     = p0;
        *(f16x8*)&xs[t * PG_ROWLEN + 8] = p1;
        __syncthreads();

        f16x8 wf  = *(const f16x8*)(wp + ks * 16);
        f16x8 xf0 = *(const f16x8*)&xs[nb * PG_ROWLEN + h * 8];
        f16x8 xf1 = *(const f16x8*)&xs[(nb + 32) * PG_ROWLEN + h * 8];
        __builtin_amdgcn_s_setprio(1);
        if (rt < 2) {
            acc[0] = MFMA_K16(wf, xf0, acc[0]);
            acc[1] = MFMA_K16(wf, xf1, acc[1]);
        } else {
            acc[0] = MFMA_K16(xf0, wf, acc[0]);
            acc[1] = MFMA_K16(xf1, wf, acc[1]);
        }
        __builtin_amdgcn_s_setprio(0);
    }

    if (rt < 2) {
        f16* dst = rt ? kws : qws;
#pragma unroll
        for (int f = 0; f < 2; ++f) {
            int n = n0 + wv * 64 + f * 32 + il;
            size_t base = ((size_t)b * Nx + n) * Dx + 4 * h;
#pragma unroll
            for (int g = 0; g < 4; ++g) {
                f16x4 o;
#pragma unroll
                for (int rr = 0; rr < 4; ++rr)
                    o[rr] = (f16)(acc[f][4 * g + rr] +
                                  bias_all[r0 + 8 * g + 4 * h + rr]);
                *(f16x4*)(dst + base + 8 * g) = o;
            }
        }
    } else {
        int c = (rt - 2) * 32 + il;
        float bvv = bias_all[r0 + il];
#pragma unroll
        for (int f = 0; f < 2; ++f) {
            size_t base = ((size_t)b * Cx + c) * Nx + n0 + wv * 64 + f * 32 + 4 * h;
#pragma unroll
            for (int g = 0; g < 4; ++g) {
                f16x4 o;
#pragma unroll
                for (int rr = 0; rr < 4; ++rr)
                    o[rr] = (f16)(acc[f][4 * g + rr] + bvv);
                *(f16x4*)(vws + base + 8 * g) = o;
            }
        }
    }
}

// ---------------------------------------------------------------------------
// Kernel C: softmax column sums  s[b][j] = sum_i exp2(E[i,j]).
// (R14-passing, unchanged.)
// ---------------------------------------------------------------------------
__global__ __launch_bounds__(256, 4) void col_stats(
    const f16* __restrict__ qhi, const f16* __restrict__ khi,
    float* __restrict__ s) {
    __shared__ float part[4][32];
    int blk = xcd_swz(144);            // 1152/8
    int jt = blk % 72;
    int b  = blk / 72;
    int j0 = jt * 32;
    int t  = threadIdx.x;
    int w  = t >> 6;
    int il = t & 31, h = (t >> 5) & 1;

    f16x8 kh[2];
#pragma unroll
    for (int ks = 0; ks < 2; ++ks)
        kh[ks] = *(const f16x8*)(khi + ((size_t)b * Nx + j0 + il) * Dx + h * 8 + ks * 16);

    f32x16 sacc = {};
    for (int it = w * 18; it < w * 18 + 18; ++it) {
        f16x8 qh[2];
#pragma unroll
        for (int ks = 0; ks < 2; ++ks)
            qh[ks] = *(const f16x8*)(qhi + ((size_t)b * Nx + it * 32 + il) * Dx + h * 8 + ks * 16);
        f32x16 e = {};
        __builtin_amdgcn_s_setprio(1);
        e = MFMA_K16(kh[0], qh[0], e);
        e = MFMA_K16(kh[1], qh[1], e);
        __builtin_amdgcn_s_setprio(0);
#pragma unroll
        for (int r = 0; r < 16; ++r) sacc[r] += EXP2F(e[r]);
    }
#pragma unroll
    for (int r = 0; r < 16; ++r) {
        float v = sacc[r];
        for (int msk = 1; msk <= 16; msk <<= 1) v += __shfl_xor(v, msk);
        if (il == 0) part[w][(r & 3) + 8 * (r >> 2) + 4 * h] = v;
    }
    __syncthreads();
    if (t < 32)
        s[(size_t)b * Nx + j0 + t] =
            part[0][t] + part[1][t] + part[2][t] + part[3][t];
}

// ---------------------------------------------------------------------------
// Kernel D: main attention.  R16: E-dedup with MERGED roles (no R15 split —
// that variant forced spill under lb(768,3) and is the suspected container
// killer). Block = (b, i64): 8 waves (cq = w>>1, cjh = w&1), 512 threads.
//  - ALL waves do PV (8 MFMA/iter, same as R14).
//  - Waves 0..3 ADDITIONALLY produce E(it=cq, jh=cjh) + exp2 + pack and
//    write the ready K16 P-frags to LDS (consumed by all waves next iter).
//  - P double-buffered, ONE barrier/iter (producers write buf[nxt],
//    consumers read buf[cur]; WAR protected by the barrier).
//  Chip totals vs R14: E-MFMA / 4, exp2+pack / 4, K+Q traffic / 4; PV same.
//  lb(512,2) -> 256-reg budget; worst-wave live set ~165 — NO forced spill.
// grid: Bx * 36 = 576 blocks, 512 threads.
// ---------------------------------------------------------------------------
__global__ __launch_bounds__(512, 2) void attn_out(
    const f16* __restrict__ qhi, const f16* __restrict__ khi,
    const f16* __restrict__ vhi,
    const float* __restrict__ s, const float* __restrict__ x,
    const float* __restrict__ gamma, float* __restrict__ out) {
    __shared__ __align__(16) float rs[Nx];              // 9216 B: -log2(s)
    __shared__ __align__(16) f16 Pb[2][2][2][2][64][8]; // 16384 B
    __shared__ float red[4][64][33];                    // 33792 B
    int blk = xcd_swz(72);             // 576/8
    int it64 = blk % 36;
    int b    = blk / 36;
    int i0   = it64 * 64;
    int t = threadIdx.x;
    int w = t >> 6;                    // wave 0..7
    int lane = t & 63;
    int il = t & 31, h = (t >> 5) & 1;
    int cq  = w >> 1;                  // c-quarter 0..3
    int cjh = w & 1;                   // j-half
    bool isprod = (w < 4);             // produces E(it=cq, jh=cjh)
    int jb = cjh * 1152;

    {   // stage -log2(sum) (512 threads)
        const f32x4* s4 = (const f32x4*)(s + (size_t)b * Nx);
        f32x4* rs4 = (f32x4*)rs;
        for (int r = t; r < Nx / 4; r += 512) {
            f32x4 v = s4[r];
            rs4[r] = (f32x4){-__log2f(v[0]), -__log2f(v[1]),
                             -__log2f(v[2]), -__log2f(v[3])};
        }
    }
    __syncthreads();

    // consumer state (all waves)
    f32x16 acc[2][2];  // [itile][cg]
#pragma unroll
    for (int a = 0; a < 2; ++a)
#pragma unroll
        for (int cg = 0; cg < 2; ++cg) acc[a][cg] = (f32x16){};
    const f16* vph = vhi + ((size_t)b * Cx + cq * 64 + il) * Nx + jb + h * 8;
    f16x8 vb[2][2][2];  // [buf][cg][gp]
#pragma unroll
    for (int cg = 0; cg < 2; ++cg)
#pragma unroll
        for (int gp = 0; gp < 2; ++gp) {
            size_t voff = (size_t)cg * 32 * Nx + gp * 16;
            vb[0][cg][gp] = *(const f16x8*)(vph + voff);
            vb[1][cg][gp] = *(const f16x8*)(vph + voff + 32);
        }

    // producer state (waves 0..3 only)
    f16x8 pq[2];
    f16x8 kb[2][2];     // K(j) lives in buf j&1
    const f16* kph = khi + ((size_t)b * Nx + jb + il) * Dx + h * 8;
    if (isprod) {
        int i32 = i0 + cq * 32;   // pit == cq for producer waves
#pragma unroll
        for (int ks = 0; ks < 2; ++ks)
            pq[ks] = *(const f16x8*)(qhi +
                ((size_t)b * Nx + i32 + il) * Dx + h * 8 + ks * 16);
#pragma unroll
        for (int ks = 0; ks < 2; ++ks) {
            kb[0][ks] = *(const f16x8*)(kph + ks * 16);
            kb[1][ks] = *(const f16x8*)(kph + 1024 + ks * 16);
        }
        // produce P(0) -> Pb[0]
        f32x16 ev;
#pragma unroll
        for (int g = 0; g < 4; ++g) {
            f32x4 rv = *(const f32x4*)&rs[jb + 8 * g + 4 * h];
#pragma unroll
            for (int jj = 0; jj < 4; ++jj) ev[4 * g + jj] = rv[jj];
        }
        f32x16 e;
        e = MFMA_K16(kb[0][0], pq[0], ev);
        e = MFMA_K16(kb[0][1], pq[1], e);
        unsigned pk[4][2];
#pragma unroll
        for (int g = 0; g < 4; ++g) {
            pk[g][0] = PKRTZ_U32(EXP2F(e[4 * g]),     EXP2F(e[4 * g + 1]));
            pk[g][1] = PKRTZ_U32(EXP2F(e[4 * g + 2]), EXP2F(e[4 * g + 3]));
        }
        *(f16x8*)&Pb[0][cq][cjh][0][lane][0] =
            swap_pack4(pk[0][0], pk[0][1], pk[1][0], pk[1][1]);
        *(f16x8*)&Pb[0][cq][cjh][1][lane][0] =
            swap_pack4(pk[2][0], pk[2][1], pk[3][0], pk[3][1]);
    }
    __syncthreads();

    for (int jt = 0; jt < 36; ++jt) {
        int cur = jt & 1, nxt = cur ^ 1;
        // ---- waves 0..3: produce P(jt+1) -> Pb[nxt] (overlaps PV below) ----
        if (isprod && jt + 1 < 36) {
            int kn = (jt + 2 < 36) ? (jt + 2) * 1024 : 0;
#pragma unroll
            for (int ks = 0; ks < 2; ++ks)
                kb[cur][ks] = *(const f16x8*)(kph + kn + ks * 16);
            int j0 = jb + (jt + 1) * 32;
            f32x16 ev;
#pragma unroll
            for (int g = 0; g < 4; ++g) {
                f32x4 rv = *(const f32x4*)&rs[j0 + 8 * g + 4 * h];
#pragma unroll
                for (int jj = 0; jj < 4; ++jj) ev[4 * g + jj] = rv[jj];
            }
            f32x16 e;
            __builtin_amdgcn_s_setprio(1);
            e = MFMA_K16(kb[nxt][0], pq[0], ev);
            e = MFMA_K16(kb[nxt][1], pq[1], e);
            __builtin_amdgcn_s_setprio(0);
            unsigned pk[4][2];
#pragma unroll
            for (int g = 0; g < 4; ++g) {
                pk[g][0] = PKRTZ_U32(EXP2F(e[4 * g]),     EXP2F(e[4 * g + 1]));
                pk[g][1] = PKRTZ_U32(EXP2F(e[4 * g + 2]), EXP2F(e[4 * g + 3]));
            }
            *(f16x8*)&Pb[nxt][cq][cjh][0][lane][0] =
                swap_pack4(pk[0][0], pk[0][1], pk[1][0], pk[1][1]);
            *(f16x8*)&Pb[nxt][cq][cjh][1][lane][0] =
                swap_pack4(pk[2][0], pk[2][1], pk[3][0], pk[3][1]);
        }
        // ---- all waves: PV(jt) from Pb[cur] ----
#pragma unroll
        for (int itile = 0; itile < 2; ++itile) {
            f16x8 p0 = *(const f16x8*)&Pb[cur][itile][cjh][0][lane][0];
            f16x8 p1 = *(const f16x8*)&Pb[cur][itile][cjh][1][lane][0];
            __builtin_amdgcn_s_setprio(1);
#pragma unroll
            for (int cg = 0; cg < 2; ++cg) {
                acc[itile][cg] = MFMA_K16(vb[cur][cg][0], p0, acc[itile][cg]);
                acc[itile][cg] = MFMA_K16(vb[cur][cg][1], p1, acc[itile][cg]);
            }
            __builtin_amdgcn_s_setprio(0);
        }
        // ---- all waves: issue V(jt+2) into slot cur (just consumed) ----
        int vn = (jt + 2 < 36) ? (jt + 2) * 32 : 0;
#pragma unroll
        for (int cg = 0; cg < 2; ++cg)
#pragma unroll
            for (int gp = 0; gp < 2; ++gp)
                vb[cur][cg][gp] =
                    *(const f16x8*)(vph + (size_t)cg * 32 * Nx + vn + gp * 16);
        __syncthreads();
    }

    // ---- epilogue: combine jh halves per cq via red (chunked per itile) ----
    float gm = gamma[0];
#pragma unroll
    for (int itile = 0; itile < 2; ++itile) {
        __syncthreads();
        if (cjh == 1) {
#pragma unroll
            for (int cg = 0; cg < 2; ++cg)
#pragma unroll
                for (int r = 0; r < 16; ++r)
                    red[cq][lane][cg * 16 + r] = acc[itile][cg][r];
        }
        __syncthreads();
        if (cjh == 0) {
#pragma unroll
            for (int cg = 0; cg < 2; ++cg)
#pragma unroll
                for (int r = 0; r < 16; ++r) {
                    int c = cq * 64 + cg * 32 + (r & 3) + 8 * (r >> 2) + 4 * h;
                    int i = i0 + itile * 32 + il;
                    size_t idx = ((size_t)b * Cx + c) * Nx + i;
                    out[idx] = x[idx] +
                        gm * (acc[itile][cg][r] + red[cq][lane][cg * 16 + r]);
                }
        }
    }
}

// ---------------------------------------------------------------------------
extern "C" void kernel_launch(void* const* d_in, const int* in_sizes, int n_in,
                              void* d_out, int out_size, void* d_ws, size_t ws_size,
                              hipStream_t stream) {
    const float* x     = (const float*)d_in[0];
    const float* Wq    = (const float*)d_in[1];
    const float* bq    = (const float*)d_in[2];
    const float* Wk    = (const float*)d_in[3];
    const float* bk    = (const float*)d_in[4];
    const float* Wv    = (const float*)d_in[5];
    const float* bv    = (const float*)d_in[6];
    const float* gamma = (const float*)d_in[7];
    float* out = (float*)d_out;

    // ws: q,k [b][n][d] f16; V [b][c][n] f16; s [b][n] f32; Wall; bias (~24 MB)
    const size_t QK = (size_t)Bx * Nx * Dx;
    const size_t VN = (size_t)Bx * Cx * Nx;
    f16* qws = (f16*)d_ws;
    f16* kws = qws + QK;
    f16* vws = kws + QK;
    float* s = (float*)(vws + VN);
    f16* Wall = (f16*)(s + (size_t)Bx * Nx);
    float* bias_all = (float*)(Wall + 320 * Cx);

    wall_prep<<<320,            256, 0, stream>>>(Wq, bq, Wk, bk, Wv, bv, Wall, bias_all);
    proj_gemm<<<Bx * 10 * 9,    256, 0, stream>>>(x, Wall, bias_all, qws, kws, vws);
    col_stats<<<Bx * 72,        256, 0, stream>>>(qws, kws, s);
    attn_out <<<Bx * 36,        512, 0, stream>>>(qws, kws, vws, s, x, gamma, out);
}